// Round 1
// baseline (2639.705 us; speedup 1.0000x reference)
//
#include <hip/hip_runtime.h>

#define N_NODES 100000
#define N_EDGES 1600000
#define IN_C    128
#define HID     256
#define NLAYER  4

// ---------------- degree / norm ----------------
__global__ void k_init(int* deg, int* fill, int n) {
    int i = blockIdx.x * blockDim.x + threadIdx.x;
    if (i < n) { deg[i] = 1; fill[i] = 0; }   // self-loop counts 1
}

__global__ void k_count(const int* __restrict__ col, int* deg, int e) {
    int i = blockIdx.x * blockDim.x + threadIdx.x;
    if (i < e) atomicAdd(&deg[col[i]], 1);
}

__global__ void k_dis(const int* __restrict__ deg, float* dis, int n) {
    int i = blockIdx.x * blockDim.x + threadIdx.x;
    if (i < n) dis[i] = rsqrtf((float)deg[i]);
}

// ---------------- exclusive scan of (deg-1) over N, single block ----------------
__global__ void k_scan(const int* __restrict__ deg, int* __restrict__ offs, int n) {
    __shared__ int wsum[17];
    __shared__ int carry;
    int lane = threadIdx.x & 63;
    int wid  = threadIdx.x >> 6;
    if (threadIdx.x == 0) carry = 0;
    __syncthreads();
    for (int base = 0; base < n; base += 4096) {
        int i0 = base + threadIdx.x * 4;
        int v[4]; int s = 0;
        #pragma unroll
        for (int t = 0; t < 4; ++t) { int i = i0 + t; v[t] = (i < n) ? (deg[i] - 1) : 0; s += v[t]; }
        int inc = s;
        #pragma unroll
        for (int off = 1; off < 64; off <<= 1) { int u = __shfl_up(inc, off); if (lane >= off) inc += u; }
        if (lane == 63) wsum[wid] = inc;
        __syncthreads();
        if (threadIdx.x == 0) {
            int r = 0;
            #pragma unroll
            for (int w = 0; w < 16; ++w) { int t = wsum[w]; wsum[w] = r; r += t; }
            wsum[16] = r;
        }
        __syncthreads();
        int boff = carry + wsum[wid] + (inc - s);
        #pragma unroll
        for (int t = 0; t < 4; ++t) { int i = i0 + t; if (i < n) offs[i] = boff; boff += v[t]; }
        __syncthreads();
        if (threadIdx.x == 0) carry += wsum[16];
        __syncthreads();
    }
    if (threadIdx.x == 0) offs[n] = carry;
}

__global__ void k_scatter(const int* __restrict__ row, const int* __restrict__ col,
                          const int* __restrict__ offs, int* fill, int* srcl, int e) {
    int i = blockIdx.x * blockDim.x + threadIdx.x;
    if (i < e) {
        int c = col[i];
        int p = offs[c] + atomicAdd(&fill[c], 1);
        srcl[p] = row[i];
    }
}

// ---------------- fp32 GEMM: C[M,Nn] = A[M,K] @ W[K,Nn] (+bias) (*scale_row) ----------------
__global__ __launch_bounds__(256) void k_gemm(
        const float* __restrict__ A, const float* __restrict__ W,
        const float* __restrict__ bias, const float* __restrict__ scale,
        float* __restrict__ C, int M, int K, int Nn) {
    __shared__ float As[64][16];   // [m][k] — stores conflict-free, reads broadcast
    __shared__ float Bs[16][64];   // [k][n]
    int bm = blockIdx.x * 64;
    int bn = blockIdx.y * 64;
    int tid = threadIdx.x;
    int tx = tid & 15, ty = tid >> 4;
    float acc[4][4] = {};
    for (int k0 = 0; k0 < K; k0 += 16) {
        #pragma unroll
        for (int j = 0; j < 4; ++j) {
            int lin = tid + j * 256;
            int m = lin >> 4, kk = lin & 15;
            int gr = bm + m;
            As[m][kk] = (gr < M) ? A[gr * K + k0 + kk] : 0.f;
        }
        #pragma unroll
        for (int j = 0; j < 4; ++j) {
            int lin = tid + j * 256;
            int kk = lin >> 6, nn = lin & 63;
            Bs[kk][nn] = W[(k0 + kk) * Nn + bn + nn];
        }
        __syncthreads();
        #pragma unroll
        for (int kk = 0; kk < 16; ++kk) {
            float a[4], b[4];
            #pragma unroll
            for (int i = 0; i < 4; ++i) a[i] = As[ty * 4 + i][kk];
            #pragma unroll
            for (int j = 0; j < 4; ++j) b[j] = Bs[kk][tx * 4 + j];
            #pragma unroll
            for (int i = 0; i < 4; ++i)
                #pragma unroll
                for (int j = 0; j < 4; ++j)
                    acc[i][j] = fmaf(a[i], b[j], acc[i][j]);
        }
        __syncthreads();
    }
    #pragma unroll
    for (int i = 0; i < 4; ++i) {
        int r = bm + ty * 4 + i;
        if (r >= M) continue;
        float sc = scale ? scale[r] : 1.f;
        #pragma unroll
        for (int j = 0; j < 4; ++j) {
            int c = bn + tx * 4 + j;
            float v = acc[i][j];
            if (bias) v += bias[c];
            C[r * Nn + c] = v * sc;
        }
    }
}

// ---------------- aggregation + bias + LayerNorm + ReLU, one wave per node ----------------
__global__ void k_agg(const float* __restrict__ hw, const int* __restrict__ srcl,
                      const int* __restrict__ offs, const float* __restrict__ dis,
                      const float* __restrict__ cb, const float* __restrict__ g,
                      const float* __restrict__ bt, float* __restrict__ hout, int n) {
    int gtid = blockIdx.x * blockDim.x + threadIdx.x;
    int node = gtid >> 6;
    int lane = threadIdx.x & 63;
    if (node >= n) return;
    const float4* hw4 = (const float4*)hw;
    float4 acc = hw4[node * 64 + lane];   // self-loop (hw already scaled by dis[src])
    float4 acc2 = make_float4(0.f, 0.f, 0.f, 0.f);
    int p = offs[node], pe = offs[node + 1];
    for (; p + 1 < pe; p += 2) {
        int s0 = srcl[p], s1 = srcl[p + 1];
        float4 v0 = hw4[s0 * 64 + lane];
        float4 v1 = hw4[s1 * 64 + lane];
        acc.x += v0.x;  acc.y += v0.y;  acc.z += v0.z;  acc.w += v0.w;
        acc2.x += v1.x; acc2.y += v1.y; acc2.z += v1.z; acc2.w += v1.w;
    }
    if (p < pe) {
        int s0 = srcl[p];
        float4 v0 = hw4[s0 * 64 + lane];
        acc.x += v0.x; acc.y += v0.y; acc.z += v0.z; acc.w += v0.w;
    }
    acc.x += acc2.x; acc.y += acc2.y; acc.z += acc2.z; acc.w += acc2.w;
    float dc = dis[node];
    int f = lane * 4;
    float h0 = fmaf(acc.x, dc, cb[f]);
    float h1 = fmaf(acc.y, dc, cb[f + 1]);
    float h2 = fmaf(acc.z, dc, cb[f + 2]);
    float h3 = fmaf(acc.w, dc, cb[f + 3]);
    float s  = h0 + h1 + h2 + h3;
    float sq = h0 * h0 + h1 * h1 + h2 * h2 + h3 * h3;
    #pragma unroll
    for (int off = 32; off; off >>= 1) { s += __shfl_down(s, off); sq += __shfl_down(sq, off); }
    s = __shfl(s, 0); sq = __shfl(sq, 0);
    float mu  = s * (1.f / 256.f);
    float var = sq * (1.f / 256.f) - mu * mu;
    float inv = rsqrtf(var + 1e-5f);
    float4 o;
    o.x = fmaxf(fmaf((h0 - mu) * inv, g[f],     bt[f]),     0.f);
    o.y = fmaxf(fmaf((h1 - mu) * inv, g[f + 1], bt[f + 1]), 0.f);
    o.z = fmaxf(fmaf((h2 - mu) * inv, g[f + 2], bt[f + 2]), 0.f);
    o.w = fmaxf(fmaf((h3 - mu) * inv, g[f + 3], bt[f + 3]), 0.f);
    ((float4*)hout)[node * 64 + lane] = o;
}

// ---------------- fused MLP head: relu(h@w1+b1)@w2+b2, one wave per 8 nodes ----------------
__global__ void k_mlp(const float* __restrict__ h, const float* __restrict__ w1,
                      const float* __restrict__ b1, const float* __restrict__ w2,
                      const float* __restrict__ b2, float* __restrict__ out, int n) {
    int gtid = blockIdx.x * blockDim.x + threadIdx.x;
    int wave = gtid >> 6;
    int lane = threadIdx.x & 63;
    int base = wave * 8;
    if (base >= n) return;
    float acc0[8], acc1[8];
    float bb0 = b1[lane], bb1 = b1[lane + 64];
    #pragma unroll
    for (int t = 0; t < 8; ++t) { acc0[t] = bb0; acc1[t] = bb1; }
    for (int k = 0; k < HID; ++k) {
        float wa = w1[k * 128 + lane];
        float wb = w1[k * 128 + 64 + lane];
        #pragma unroll
        for (int t = 0; t < 8; ++t) {
            float hv = h[(base + t) * HID + k];   // n % 8 == 0, always in range
            acc0[t] = fmaf(hv, wa, acc0[t]);
            acc1[t] = fmaf(hv, wb, acc1[t]);
        }
    }
    float w2a = w2[lane], w2b = w2[lane + 64];
    float b2v = b2[0];
    #pragma unroll
    for (int t = 0; t < 8; ++t) {
        float r = fmaxf(acc0[t], 0.f) * w2a + fmaxf(acc1[t], 0.f) * w2b;
        #pragma unroll
        for (int off = 32; off; off >>= 1) r += __shfl_down(r, off);
        if (lane == 0) out[base + t] = r + b2v;
    }
}

extern "C" void kernel_launch(void* const* d_in, const int* in_sizes, int n_in,
                              void* d_out, int out_size, void* d_ws, size_t ws_size,
                              hipStream_t stream) {
    const float* x      = (const float*)d_in[0];
    const int*   ei     = (const int*)d_in[1];     // (2,E) int32
    const float* enc_w  = (const float*)d_in[2];
    const float* enc_b  = (const float*)d_in[3];
    const float* conv_w = (const float*)d_in[4];
    const float* conv_b = (const float*)d_in[5];
    const float* ln_g   = (const float*)d_in[6];
    const float* ln_b   = (const float*)d_in[7];
    const float* w1     = (const float*)d_in[8];
    const float* b1     = (const float*)d_in[9];
    const float* w2     = (const float*)d_in[10];
    const float* b2     = (const float*)d_in[11];
    float* out = (float*)d_out;

    char* ws = (char*)d_ws;
    size_t off = 0;
    auto alloc = [&](size_t bytes) -> void* {
        void* p = ws + off;
        off = (off + bytes + 255) & ~(size_t)255;
        return p;
    };
    int*   deg  = (int*)alloc((size_t)N_NODES * 4);
    int*   fill = (int*)alloc((size_t)N_NODES * 4);
    int*   offs = (int*)alloc((size_t)(N_NODES + 1) * 4);
    int*   srcl = (int*)alloc((size_t)N_EDGES * 4);
    float* dis  = (float*)alloc((size_t)N_NODES * 4);
    float* h    = (float*)alloc((size_t)N_NODES * HID * 4);
    float* hw   = (float*)alloc((size_t)N_NODES * HID * 4);

    const int* row = ei;             // sources
    const int* col = ei + N_EDGES;   // targets

    int nb = (N_NODES + 255) / 256;
    int eb = (N_EDGES + 255) / 256;

    k_init<<<nb, 256, 0, stream>>>(deg, fill, N_NODES);
    k_count<<<eb, 256, 0, stream>>>(col, deg, N_EDGES);
    k_dis<<<nb, 256, 0, stream>>>(deg, dis, N_NODES);
    k_scan<<<1, 1024, 0, stream>>>(deg, offs, N_NODES);
    k_scatter<<<eb, 256, 0, stream>>>(row, col, offs, fill, srcl, N_EDGES);

    dim3 ggrid((N_NODES + 63) / 64, HID / 64);
    // encoder: h = x @ enc_w + enc_b
    k_gemm<<<ggrid, 256, 0, stream>>>(x, enc_w, enc_b, nullptr, h, N_NODES, IN_C, HID);

    for (int l = 0; l < NLAYER; ++l) {
        // hw = (h @ conv_w[l]) * dis[row]   (bias added after aggregation)
        k_gemm<<<ggrid, 256, 0, stream>>>(h, conv_w + (size_t)l * HID * HID, nullptr, dis,
                                          hw, N_NODES, HID, HID);
        k_agg<<<(N_NODES * 64 + 255) / 256, 256, 0, stream>>>(
            hw, srcl, offs, dis, conv_b + l * HID, ln_g + l * HID, ln_b + l * HID, h, N_NODES);
    }

    // head: out = relu(h@w1+b1)@w2+b2
    int waves = N_NODES / 8;                    // 12500
    k_mlp<<<(waves * 64 + 255) / 256, 256, 0, stream>>>(h, w1, b1, w2, b2, out, N_NODES);
}

// Round 2
// 1498.150 us; speedup vs baseline: 1.7620x; 1.7620x over previous
//
#include <hip/hip_runtime.h>

#define N_NODES 100000
#define N_EDGES 1600000
#define IN_C    128
#define HID     256
#define NLAYER  4

typedef __attribute__((ext_vector_type(8))) __bf16 bf16x8;
typedef __attribute__((ext_vector_type(4))) float  floatx4;

__device__ inline unsigned short f2b(float f) {
    unsigned u = __builtin_bit_cast(unsigned, f);
    return (unsigned short)((u + 0x7fffu + ((u >> 16) & 1u)) >> 16);
}

// ---------------- degree / norm ----------------
__global__ void k_init(int* deg, int* fill, int n) {
    int i = blockIdx.x * blockDim.x + threadIdx.x;
    if (i < n) { deg[i] = 1; fill[i] = 0; }   // self-loop counts 1
}

__global__ void k_count(const int* __restrict__ col, int* deg, int e) {
    int i = blockIdx.x * blockDim.x + threadIdx.x;
    if (i < e) atomicAdd(&deg[col[i]], 1);
}

__global__ void k_dis(const int* __restrict__ deg, float* dis, int n) {
    int i = blockIdx.x * blockDim.x + threadIdx.x;
    if (i < n) dis[i] = rsqrtf((float)deg[i]);
}

// ---------------- exclusive scan of (deg-1) over N, single block ----------------
__global__ void k_scan(const int* __restrict__ deg, int* __restrict__ offs, int n) {
    __shared__ int wsum[17];
    __shared__ int carry;
    int lane = threadIdx.x & 63;
    int wid  = threadIdx.x >> 6;
    if (threadIdx.x == 0) carry = 0;
    __syncthreads();
    for (int base = 0; base < n; base += 4096) {
        int i0 = base + threadIdx.x * 4;
        int v[4]; int s = 0;
        #pragma unroll
        for (int t = 0; t < 4; ++t) { int i = i0 + t; v[t] = (i < n) ? (deg[i] - 1) : 0; s += v[t]; }
        int inc = s;
        #pragma unroll
        for (int off = 1; off < 64; off <<= 1) { int u = __shfl_up(inc, off); if (lane >= off) inc += u; }
        if (lane == 63) wsum[wid] = inc;
        __syncthreads();
        if (threadIdx.x == 0) {
            int r = 0;
            #pragma unroll
            for (int w = 0; w < 16; ++w) { int t = wsum[w]; wsum[w] = r; r += t; }
            wsum[16] = r;
        }
        __syncthreads();
        int boff = carry + wsum[wid] + (inc - s);
        #pragma unroll
        for (int t = 0; t < 4; ++t) { int i = i0 + t; if (i < n) offs[i] = boff; boff += v[t]; }
        __syncthreads();
        if (threadIdx.x == 0) carry += wsum[16];
        __syncthreads();
    }
    if (threadIdx.x == 0) offs[n] = carry;
}

__global__ void k_scatter(const int* __restrict__ row, const int* __restrict__ col,
                          const int* __restrict__ offs, int* fill, int* srcl, int e) {
    int i = blockIdx.x * blockDim.x + threadIdx.x;
    if (i < e) {
        int c = col[i];
        int p = offs[c] + atomicAdd(&fill[c], 1);
        srcl[p] = row[i];
    }
}

// ---------------- conversions ----------------
__global__ void k_f2b4(const float* __restrict__ src, unsigned short* __restrict__ dst, int n4) {
    int i = blockIdx.x * blockDim.x + threadIdx.x;
    if (i < n4) {
        float4 v = ((const float4*)src)[i];
        ushort4 o;
        o.x = f2b(v.x); o.y = f2b(v.y); o.z = f2b(v.z); o.w = f2b(v.w);
        ((ushort4*)dst)[i] = o;
    }
}

// W [K][Nn] fp32 row-major  ->  Wt [Nn][K] bf16
__global__ void k_wt(const float* __restrict__ W, unsigned short* __restrict__ Wt, int K, int Nn) {
    int idx = blockIdx.x * blockDim.x + threadIdx.x;
    if (idx < K * Nn) {
        int k = idx / Nn, n = idx % Nn;
        Wt[n * K + k] = f2b(W[idx]);
    }
}

// ---------------- MFMA GEMM: C[M,Nn] = A[M,K](bf16) @ Wt[Nn,K](bf16)^T ----------------
// MODE 0: enc   (+bias,      store bf16)
// MODE 1: conv  (*scale[row],store fp32)
// MODE 2: lin1  (+bias,relu, store fp32)
template<int MODE>
__global__ __launch_bounds__(256) void k_mm(
        const unsigned short* __restrict__ A,
        const unsigned short* __restrict__ Wt,
        const float* __restrict__ bias, const float* __restrict__ scale,
        void* __restrict__ Cout, int M, int K, int Nn) {
    __shared__ unsigned short As[128 * 32];   // [m][k], BK=32, 8 KB
    __shared__ unsigned short Bs[128 * 32];   // [n][k], 8 KB
    const int tid  = threadIdx.x;
    const int lane = tid & 63;
    const int w    = tid >> 6;
    const int bm   = blockIdx.x * 128;
    const int bn   = blockIdx.y * 128;

    // staging: thread handles flat slots i0=tid, i1=tid+256; row=i>>2, kq=i&3 (8 elems each)
    const int i0 = tid, i1 = tid + 256;
    const int r0 = i0 >> 2, r1 = i1 >> 2;
    const int q0 = i0 & 3,  q1 = i1 & 3;
    const int a_off0 = min(bm + r0, M - 1) * K + q0 * 8;
    const int a_off1 = min(bm + r1, M - 1) * K + q1 * 8;
    const int b_off0 = (bn + r0) * K + q0 * 8;
    const int b_off1 = (bn + r1) * K + q1 * 8;

    uint4 ra0, ra1, rb0, rb1;
    floatx4 acc[4][4];
    #pragma unroll
    for (int i = 0; i < 4; ++i)
        #pragma unroll
        for (int j = 0; j < 4; ++j)
            acc[i][j] = (floatx4){0.f, 0.f, 0.f, 0.f};

    const int wm = (w & 1) * 64;
    const int wn = (w >> 1) * 64;
    const int fm = lane & 15;       // row/col within 16-tile
    const int fq = (lane >> 4) * 8; // k-offset of this lane's 8 elements

    ra0 = *(const uint4*)(A  + a_off0);
    ra1 = *(const uint4*)(A  + a_off1);
    rb0 = *(const uint4*)(Wt + b_off0);
    rb1 = *(const uint4*)(Wt + b_off1);

    const int KT = K >> 5;
    for (int kt = 0; kt < KT; ++kt) {
        ((uint4*)As)[i0] = ra0; ((uint4*)As)[i1] = ra1;
        ((uint4*)Bs)[i0] = rb0; ((uint4*)Bs)[i1] = rb1;
        __syncthreads();
        if (kt + 1 < KT) {
            int k0 = (kt + 1) << 5;
            ra0 = *(const uint4*)(A  + a_off0 + k0);
            ra1 = *(const uint4*)(A  + a_off1 + k0);
            rb0 = *(const uint4*)(Wt + b_off0 + k0);
            rb1 = *(const uint4*)(Wt + b_off1 + k0);
        }
        bf16x8 af[4], bf[4];
        #pragma unroll
        for (int i = 0; i < 4; ++i)
            af[i] = *(const bf16x8*)(const void*)(As + (wm + i * 16 + fm) * 32 + fq);
        #pragma unroll
        for (int j = 0; j < 4; ++j)
            bf[j] = *(const bf16x8*)(const void*)(Bs + (wn + j * 16 + fm) * 32 + fq);
        #pragma unroll
        for (int i = 0; i < 4; ++i)
            #pragma unroll
            for (int j = 0; j < 4; ++j)
                acc[i][j] = __builtin_amdgcn_mfma_f32_16x16x32_bf16(af[i], bf[j], acc[i][j], 0, 0, 0);
        __syncthreads();
    }

    // epilogue: C/D layout col=lane&15, row=(lane>>4)*4+reg
    const int quad = lane >> 4;
    #pragma unroll
    for (int i = 0; i < 4; ++i) {
        #pragma unroll
        for (int r = 0; r < 4; ++r) {
            int row = bm + wm + i * 16 + quad * 4 + r;
            if (row >= M) continue;
            float sc = (MODE == 1) ? scale[row] : 1.f;
            #pragma unroll
            for (int j = 0; j < 4; ++j) {
                int colg = bn + wn + j * 16 + fm;
                float v = acc[i][j][r];
                if (MODE == 0 || MODE == 2) v += bias[colg];
                if (MODE == 1) v *= sc;
                if (MODE == 2) v = fmaxf(v, 0.f);
                if (MODE == 0)
                    ((unsigned short*)Cout)[(size_t)row * Nn + colg] = f2b(v);
                else
                    ((float*)Cout)[(size_t)row * Nn + colg] = v;
            }
        }
    }
}

// ---------------- aggregation + bias + LayerNorm + ReLU, one wave per node ----------------
// reads hw fp32, writes h bf16
__global__ void k_agg(const float* __restrict__ hw, const int* __restrict__ srcl,
                      const int* __restrict__ offs, const float* __restrict__ dis,
                      const float* __restrict__ cb, const float* __restrict__ g,
                      const float* __restrict__ bt, unsigned short* __restrict__ hout, int n) {
    int gtid = blockIdx.x * blockDim.x + threadIdx.x;
    int node = gtid >> 6;
    int lane = threadIdx.x & 63;
    if (node >= n) return;
    const float4* hw4 = (const float4*)hw;
    float4 acc = hw4[node * 64 + lane];   // self-loop (hw already scaled by dis[src])
    float4 acc2 = make_float4(0.f, 0.f, 0.f, 0.f);
    int p = offs[node], pe = offs[node + 1];
    for (; p + 1 < pe; p += 2) {
        int s0 = srcl[p], s1 = srcl[p + 1];
        float4 v0 = hw4[s0 * 64 + lane];
        float4 v1 = hw4[s1 * 64 + lane];
        acc.x += v0.x;  acc.y += v0.y;  acc.z += v0.z;  acc.w += v0.w;
        acc2.x += v1.x; acc2.y += v1.y; acc2.z += v1.z; acc2.w += v1.w;
    }
    if (p < pe) {
        int s0 = srcl[p];
        float4 v0 = hw4[s0 * 64 + lane];
        acc.x += v0.x; acc.y += v0.y; acc.z += v0.z; acc.w += v0.w;
    }
    acc.x += acc2.x; acc.y += acc2.y; acc.z += acc2.z; acc.w += acc2.w;
    float dc = dis[node];
    int f = lane * 4;
    float h0 = fmaf(acc.x, dc, cb[f]);
    float h1 = fmaf(acc.y, dc, cb[f + 1]);
    float h2 = fmaf(acc.z, dc, cb[f + 2]);
    float h3 = fmaf(acc.w, dc, cb[f + 3]);
    float s  = h0 + h1 + h2 + h3;
    float sq = h0 * h0 + h1 * h1 + h2 * h2 + h3 * h3;
    #pragma unroll
    for (int off = 32; off; off >>= 1) { s += __shfl_down(s, off); sq += __shfl_down(sq, off); }
    s = __shfl(s, 0); sq = __shfl(sq, 0);
    float mu  = s * (1.f / 256.f);
    float var = sq * (1.f / 256.f) - mu * mu;
    float inv = rsqrtf(var + 1e-5f);
    ushort4 o;
    o.x = f2b(fmaxf(fmaf((h0 - mu) * inv, g[f],     bt[f]),     0.f));
    o.y = f2b(fmaxf(fmaf((h1 - mu) * inv, g[f + 1], bt[f + 1]), 0.f));
    o.z = f2b(fmaxf(fmaf((h2 - mu) * inv, g[f + 2], bt[f + 2]), 0.f));
    o.w = f2b(fmaxf(fmaf((h3 - mu) * inv, g[f + 3], bt[f + 3]), 0.f));
    ((ushort4*)hout)[node * 64 + lane] = o;
}

// ---------------- lin2: out[node] = dot(hid1[node,:128], w2) + b2 ----------------
__global__ void k_lin2(const float* __restrict__ hid, const float* __restrict__ w2,
                       const float* __restrict__ b2, float* __restrict__ out, int n) {
    int gtid = blockIdx.x * blockDim.x + threadIdx.x;
    int node = gtid >> 6;
    int lane = threadIdx.x & 63;
    if (node >= n) return;
    float2 h = ((const float2*)hid)[node * 64 + lane];
    float2 wv = ((const float2*)w2)[lane];
    float r = h.x * wv.x + h.y * wv.y;
    #pragma unroll
    for (int off = 32; off; off >>= 1) r += __shfl_down(r, off);
    if (lane == 0) out[node] = r + b2[0];
}

extern "C" void kernel_launch(void* const* d_in, const int* in_sizes, int n_in,
                              void* d_out, int out_size, void* d_ws, size_t ws_size,
                              hipStream_t stream) {
    const float* x      = (const float*)d_in[0];
    const int*   ei     = (const int*)d_in[1];     // (2,E) int32
    const float* enc_w  = (const float*)d_in[2];
    const float* enc_b  = (const float*)d_in[3];
    const float* conv_w = (const float*)d_in[4];
    const float* conv_b = (const float*)d_in[5];
    const float* ln_g   = (const float*)d_in[6];
    const float* ln_b   = (const float*)d_in[7];
    const float* w1     = (const float*)d_in[8];
    const float* b1     = (const float*)d_in[9];
    const float* w2     = (const float*)d_in[10];
    const float* b2     = (const float*)d_in[11];
    float* out = (float*)d_out;

    char* ws = (char*)d_ws;
    size_t off = 0;
    auto alloc = [&](size_t bytes) -> void* {
        void* p = ws + off;
        off = (off + bytes + 255) & ~(size_t)255;
        return p;
    };
    int*   deg  = (int*)alloc((size_t)N_NODES * 4);
    int*   fill = (int*)alloc((size_t)N_NODES * 4);
    int*   offs = (int*)alloc((size_t)(N_NODES + 1) * 4);
    int*   srcl = (int*)alloc((size_t)N_EDGES * 4);
    float* dis  = (float*)alloc((size_t)N_NODES * 4);
    unsigned short* hb = (unsigned short*)alloc((size_t)N_NODES * HID * 2);   // h, bf16
    // R1 region: xb (bf16 x) -> hw (fp32) -> hid1 (fp32), lifetimes disjoint
    char* R1 = (char*)alloc((size_t)N_NODES * HID * 4);
    unsigned short* xb   = (unsigned short*)R1;
    float*          hw   = (float*)R1;
    float*          hid1 = (float*)R1;
    unsigned short* enc_t  = (unsigned short*)alloc((size_t)IN_C * HID * 2);
    unsigned short* conv_t = (unsigned short*)alloc((size_t)NLAYER * HID * HID * 2);
    unsigned short* lin1_t = (unsigned short*)alloc((size_t)HID * (HID / 2) * 2);

    const int* row = ei;             // sources
    const int* col = ei + N_EDGES;   // targets

    int nb = (N_NODES + 255) / 256;
    int eb = (N_EDGES + 255) / 256;

    k_init<<<nb, 256, 0, stream>>>(deg, fill, N_NODES);
    k_count<<<eb, 256, 0, stream>>>(col, deg, N_EDGES);
    k_dis<<<nb, 256, 0, stream>>>(deg, dis, N_NODES);
    k_scan<<<1, 1024, 0, stream>>>(deg, offs, N_NODES);
    k_scatter<<<eb, 256, 0, stream>>>(row, col, offs, fill, srcl, N_EDGES);

    // conversions
    int xn4 = N_NODES * IN_C / 4;
    k_f2b4<<<(xn4 + 255) / 256, 256, 0, stream>>>(x, xb, xn4);
    k_wt<<<(IN_C * HID + 255) / 256, 256, 0, stream>>>(enc_w, enc_t, IN_C, HID);
    for (int l = 0; l < NLAYER; ++l)
        k_wt<<<(HID * HID + 255) / 256, 256, 0, stream>>>(
            conv_w + (size_t)l * HID * HID, conv_t + (size_t)l * HID * HID, HID, HID);
    k_wt<<<(HID * (HID / 2) + 255) / 256, 256, 0, stream>>>(w1, lin1_t, HID, HID / 2);

    // encoder: h = bf16(x @ enc_w + enc_b)
    {
        dim3 g((N_NODES + 127) / 128, HID / 128);
        k_mm<0><<<g, 256, 0, stream>>>(xb, enc_t, enc_b, nullptr, hb, N_NODES, IN_C, HID);
    }

    for (int l = 0; l < NLAYER; ++l) {
        dim3 g((N_NODES + 127) / 128, HID / 128);
        k_mm<1><<<g, 256, 0, stream>>>(hb, conv_t + (size_t)l * HID * HID, nullptr, dis,
                                       hw, N_NODES, HID, HID);
        k_agg<<<(N_NODES * 64 + 255) / 256, 256, 0, stream>>>(
            hw, srcl, offs, dis, conv_b + l * HID, ln_g + l * HID, ln_b + l * HID, hb, N_NODES);
    }

    // head
    {
        dim3 g((N_NODES + 127) / 128, 1);
        k_mm<2><<<g, 256, 0, stream>>>(hb, lin1_t, b1, nullptr, hid1, N_NODES, HID, HID / 2);
    }
    k_lin2<<<(N_NODES * 64 + 255) / 256, 256, 0, stream>>>(hid1, w2, b2, out, N_NODES);
}

// Round 3
// 1064.720 us; speedup vs baseline: 2.4792x; 1.4071x over previous
//
#include <hip/hip_runtime.h>

#define N_NODES 100000
#define N_EDGES 1600000
#define IN_C    128
#define HID     256
#define NLAYER  4

typedef __attribute__((ext_vector_type(8))) __bf16 bf16x8;
typedef __attribute__((ext_vector_type(4))) float  floatx4;

__device__ inline unsigned short f2b(float f) {
    unsigned u = __builtin_bit_cast(unsigned, f);
    return (unsigned short)((u + 0x7fffu + ((u >> 16) & 1u)) >> 16);
}
__device__ inline float b2f(unsigned short s) {
    unsigned u = ((unsigned)s) << 16;
    return __builtin_bit_cast(float, u);
}

// ---------------- degree / norm ----------------
__global__ void k_init(int* deg, int* fill, int n) {
    int i = blockIdx.x * blockDim.x + threadIdx.x;
    if (i < n) { deg[i] = 1; fill[i] = 0; }   // self-loop counts 1
}

__global__ void k_count(const int* __restrict__ col, int* deg, int e) {
    int i = blockIdx.x * blockDim.x + threadIdx.x;
    if (i < e) atomicAdd(&deg[col[i]], 1);
}

__global__ void k_dis(const int* __restrict__ deg, float* dis, int n) {
    int i = blockIdx.x * blockDim.x + threadIdx.x;
    if (i < n) dis[i] = rsqrtf((float)deg[i]);
}

// ---------------- exclusive scan of (deg-1) over N, single block ----------------
__global__ void k_scan(const int* __restrict__ deg, int* __restrict__ offs, int n) {
    __shared__ int wsum[17];
    __shared__ int carry;
    int lane = threadIdx.x & 63;
    int wid  = threadIdx.x >> 6;
    if (threadIdx.x == 0) carry = 0;
    __syncthreads();
    for (int base = 0; base < n; base += 4096) {
        int i0 = base + threadIdx.x * 4;
        int v[4]; int s = 0;
        #pragma unroll
        for (int t = 0; t < 4; ++t) { int i = i0 + t; v[t] = (i < n) ? (deg[i] - 1) : 0; s += v[t]; }
        int inc = s;
        #pragma unroll
        for (int off = 1; off < 64; off <<= 1) { int u = __shfl_up(inc, off); if (lane >= off) inc += u; }
        if (lane == 63) wsum[wid] = inc;
        __syncthreads();
        if (threadIdx.x == 0) {
            int r = 0;
            #pragma unroll
            for (int w = 0; w < 16; ++w) { int t = wsum[w]; wsum[w] = r; r += t; }
            wsum[16] = r;
        }
        __syncthreads();
        int boff = carry + wsum[wid] + (inc - s);
        #pragma unroll
        for (int t = 0; t < 4; ++t) { int i = i0 + t; if (i < n) offs[i] = boff; boff += v[t]; }
        __syncthreads();
        if (threadIdx.x == 0) carry += wsum[16];
        __syncthreads();
    }
    if (threadIdx.x == 0) offs[n] = carry;
}

__global__ void k_scatter(const int* __restrict__ row, const int* __restrict__ col,
                          const int* __restrict__ offs, int* fill, int* srcl, int e) {
    int i = blockIdx.x * blockDim.x + threadIdx.x;
    if (i < e) {
        int c = col[i];
        int p = offs[c] + atomicAdd(&fill[c], 1);
        srcl[p] = row[i];
    }
}

// ---------------- conversions ----------------
__global__ void k_f2b4(const float* __restrict__ src, unsigned short* __restrict__ dst, int n4) {
    int i = blockIdx.x * blockDim.x + threadIdx.x;
    if (i < n4) {
        float4 v = ((const float4*)src)[i];
        ushort4 o;
        o.x = f2b(v.x); o.y = f2b(v.y); o.z = f2b(v.z); o.w = f2b(v.w);
        ((ushort4*)dst)[i] = o;
    }
}

// W [K][Nn] fp32 row-major  ->  Wt [Nn][K] bf16
__global__ void k_wt(const float* __restrict__ W, unsigned short* __restrict__ Wt, int K, int Nn) {
    int idx = blockIdx.x * blockDim.x + threadIdx.x;
    if (idx < K * Nn) {
        int k = idx / Nn, n = idx % Nn;
        Wt[n * K + k] = f2b(W[idx]);
    }
}

// ---------------- MFMA GEMM: C[M,Nn] = A[M,K](bf16) @ Wt[Nn,K](bf16)^T ----------------
// MODE 0: enc   (+bias,       store bf16)
// MODE 1: conv  (*scale[row], store bf16)
// MODE 2: lin1  (+bias,relu,  store fp32)
template<int MODE>
__global__ __launch_bounds__(256) void k_mm(
        const unsigned short* __restrict__ A,
        const unsigned short* __restrict__ Wt,
        const float* __restrict__ bias, const float* __restrict__ scale,
        void* __restrict__ Cout, int M, int K, int Nn) {
    __shared__ unsigned short As[128 * 32];   // [m][k], BK=32, 8 KB
    __shared__ unsigned short Bs[128 * 32];   // [n][k], 8 KB
    const int tid  = threadIdx.x;
    const int lane = tid & 63;
    const int w    = tid >> 6;
    const int bm   = blockIdx.x * 128;
    const int bn   = blockIdx.y * 128;

    const int i0 = tid, i1 = tid + 256;
    const int r0 = i0 >> 2, r1 = i1 >> 2;
    const int q0 = i0 & 3,  q1 = i1 & 3;
    const int a_off0 = min(bm + r0, M - 1) * K + q0 * 8;
    const int a_off1 = min(bm + r1, M - 1) * K + q1 * 8;
    const int b_off0 = (bn + r0) * K + q0 * 8;
    const int b_off1 = (bn + r1) * K + q1 * 8;

    uint4 ra0, ra1, rb0, rb1;
    floatx4 acc[4][4];
    #pragma unroll
    for (int i = 0; i < 4; ++i)
        #pragma unroll
        for (int j = 0; j < 4; ++j)
            acc[i][j] = (floatx4){0.f, 0.f, 0.f, 0.f};

    const int wm = (w & 1) * 64;
    const int wn = (w >> 1) * 64;
    const int fm = lane & 15;
    const int fq = (lane >> 4) * 8;

    ra0 = *(const uint4*)(A  + a_off0);
    ra1 = *(const uint4*)(A  + a_off1);
    rb0 = *(const uint4*)(Wt + b_off0);
    rb1 = *(const uint4*)(Wt + b_off1);

    const int KT = K >> 5;
    for (int kt = 0; kt < KT; ++kt) {
        ((uint4*)As)[i0] = ra0; ((uint4*)As)[i1] = ra1;
        ((uint4*)Bs)[i0] = rb0; ((uint4*)Bs)[i1] = rb1;
        __syncthreads();
        if (kt + 1 < KT) {
            int k0 = (kt + 1) << 5;
            ra0 = *(const uint4*)(A  + a_off0 + k0);
            ra1 = *(const uint4*)(A  + a_off1 + k0);
            rb0 = *(const uint4*)(Wt + b_off0 + k0);
            rb1 = *(const uint4*)(Wt + b_off1 + k0);
        }
        bf16x8 af[4], bf[4];
        #pragma unroll
        for (int i = 0; i < 4; ++i)
            af[i] = *(const bf16x8*)(const void*)(As + (wm + i * 16 + fm) * 32 + fq);
        #pragma unroll
        for (int j = 0; j < 4; ++j)
            bf[j] = *(const bf16x8*)(const void*)(Bs + (wn + j * 16 + fm) * 32 + fq);
        #pragma unroll
        for (int i = 0; i < 4; ++i)
            #pragma unroll
            for (int j = 0; j < 4; ++j)
                acc[i][j] = __builtin_amdgcn_mfma_f32_16x16x32_bf16(af[i], bf[j], acc[i][j], 0, 0, 0);
        __syncthreads();
    }

    // epilogue: C/D layout col=lane&15, row=(lane>>4)*4+reg
    const int quad = lane >> 4;
    #pragma unroll
    for (int i = 0; i < 4; ++i) {
        #pragma unroll
        for (int r = 0; r < 4; ++r) {
            int row = bm + wm + i * 16 + quad * 4 + r;
            if (row >= M) continue;
            float sc = (MODE == 1) ? scale[row] : 1.f;
            #pragma unroll
            for (int j = 0; j < 4; ++j) {
                int colg = bn + wn + j * 16 + fm;
                float v = acc[i][j][r];
                if (MODE == 0 || MODE == 2) v += bias[colg];
                if (MODE == 1) v *= sc;
                if (MODE == 2) v = fmaxf(v, 0.f);
                if (MODE == 2)
                    ((float*)Cout)[(size_t)row * Nn + colg] = v;
                else
                    ((unsigned short*)Cout)[(size_t)row * Nn + colg] = f2b(v);
            }
        }
    }
}

// ---------------- aggregation + bias + LayerNorm + ReLU, one wave per node ----------------
// reads hw bf16, accumulates fp32, writes h bf16
__global__ void k_agg(const unsigned short* __restrict__ hw, const int* __restrict__ srcl,
                      const int* __restrict__ offs, const float* __restrict__ dis,
                      const float* __restrict__ cb, const float* __restrict__ g,
                      const float* __restrict__ bt, unsigned short* __restrict__ hout, int n) {
    int gtid = blockIdx.x * blockDim.x + threadIdx.x;
    int node = gtid >> 6;
    int lane = threadIdx.x & 63;
    if (node >= n) return;
    const ushort4* hw4 = (const ushort4*)hw;
    ushort4 sv = hw4[node * 64 + lane];   // self-loop (hw already scaled by dis[src])
    float a0 = b2f(sv.x), a1 = b2f(sv.y), a2 = b2f(sv.z), a3 = b2f(sv.w);
    float c0 = 0.f, c1 = 0.f, c2 = 0.f, c3 = 0.f;
    int p = offs[node], pe = offs[node + 1];
    for (; p + 1 < pe; p += 2) {
        int s0 = srcl[p], s1 = srcl[p + 1];
        ushort4 v0 = hw4[s0 * 64 + lane];
        ushort4 v1 = hw4[s1 * 64 + lane];
        a0 += b2f(v0.x); a1 += b2f(v0.y); a2 += b2f(v0.z); a3 += b2f(v0.w);
        c0 += b2f(v1.x); c1 += b2f(v1.y); c2 += b2f(v1.z); c3 += b2f(v1.w);
    }
    if (p < pe) {
        int s0 = srcl[p];
        ushort4 v0 = hw4[s0 * 64 + lane];
        a0 += b2f(v0.x); a1 += b2f(v0.y); a2 += b2f(v0.z); a3 += b2f(v0.w);
    }
    a0 += c0; a1 += c1; a2 += c2; a3 += c3;
    float dc = dis[node];
    int f = lane * 4;
    float h0 = fmaf(a0, dc, cb[f]);
    float h1 = fmaf(a1, dc, cb[f + 1]);
    float h2 = fmaf(a2, dc, cb[f + 2]);
    float h3 = fmaf(a3, dc, cb[f + 3]);
    float s  = h0 + h1 + h2 + h3;
    float sq = h0 * h0 + h1 * h1 + h2 * h2 + h3 * h3;
    #pragma unroll
    for (int off = 32; off; off >>= 1) { s += __shfl_down(s, off); sq += __shfl_down(sq, off); }
    s = __shfl(s, 0); sq = __shfl(sq, 0);
    float mu  = s * (1.f / 256.f);
    float var = sq * (1.f / 256.f) - mu * mu;
    float inv = rsqrtf(var + 1e-5f);
    ushort4 o;
    o.x = f2b(fmaxf(fmaf((h0 - mu) * inv, g[f],     bt[f]),     0.f));
    o.y = f2b(fmaxf(fmaf((h1 - mu) * inv, g[f + 1], bt[f + 1]), 0.f));
    o.z = f2b(fmaxf(fmaf((h2 - mu) * inv, g[f + 2], bt[f + 2]), 0.f));
    o.w = f2b(fmaxf(fmaf((h3 - mu) * inv, g[f + 3], bt[f + 3]), 0.f));
    ((ushort4*)hout)[node * 64 + lane] = o;
}

// ---------------- lin2: out[node] = dot(hid1[node,:128], w2) + b2 ----------------
__global__ void k_lin2(const float* __restrict__ hid, const float* __restrict__ w2,
                       const float* __restrict__ b2, float* __restrict__ out, int n) {
    int gtid = blockIdx.x * blockDim.x + threadIdx.x;
    int node = gtid >> 6;
    int lane = threadIdx.x & 63;
    if (node >= n) return;
    float2 h = ((const float2*)hid)[node * 64 + lane];
    float2 wv = ((const float2*)w2)[lane];
    float r = h.x * wv.x + h.y * wv.y;
    #pragma unroll
    for (int off = 32; off; off >>= 1) r += __shfl_down(r, off);
    if (lane == 0) out[node] = r + b2[0];
}

extern "C" void kernel_launch(void* const* d_in, const int* in_sizes, int n_in,
                              void* d_out, int out_size, void* d_ws, size_t ws_size,
                              hipStream_t stream) {
    const float* x      = (const float*)d_in[0];
    const int*   ei     = (const int*)d_in[1];     // (2,E) int32
    const float* enc_w  = (const float*)d_in[2];
    const float* enc_b  = (const float*)d_in[3];
    const float* conv_w = (const float*)d_in[4];
    const float* conv_b = (const float*)d_in[5];
    const float* ln_g   = (const float*)d_in[6];
    const float* ln_b   = (const float*)d_in[7];
    const float* w1     = (const float*)d_in[8];
    const float* b1     = (const float*)d_in[9];
    const float* w2     = (const float*)d_in[10];
    const float* b2     = (const float*)d_in[11];
    float* out = (float*)d_out;

    char* ws = (char*)d_ws;
    size_t off = 0;
    auto alloc = [&](size_t bytes) -> void* {
        void* p = ws + off;
        off = (off + bytes + 255) & ~(size_t)255;
        return p;
    };
    int*   deg  = (int*)alloc((size_t)N_NODES * 4);
    int*   fill = (int*)alloc((size_t)N_NODES * 4);
    int*   offs = (int*)alloc((size_t)(N_NODES + 1) * 4);
    int*   srcl = (int*)alloc((size_t)N_EDGES * 4);
    float* dis  = (float*)alloc((size_t)N_NODES * 4);
    unsigned short* hb = (unsigned short*)alloc((size_t)N_NODES * HID * 2);   // h, bf16
    unsigned short* hw = (unsigned short*)alloc((size_t)N_NODES * HID * 2);   // hw, bf16
    // R2 region: xb (bf16 x) then hid1 (fp32), lifetimes disjoint
    char* R2 = (char*)alloc((size_t)N_NODES * (HID / 2) * 4);
    unsigned short* xb   = (unsigned short*)R2;
    float*          hid1 = (float*)R2;
    unsigned short* enc_t  = (unsigned short*)alloc((size_t)IN_C * HID * 2);
    unsigned short* conv_t = (unsigned short*)alloc((size_t)NLAYER * HID * HID * 2);
    unsigned short* lin1_t = (unsigned short*)alloc((size_t)HID * (HID / 2) * 2);

    const int* row = ei;             // sources
    const int* col = ei + N_EDGES;   // targets

    int nb = (N_NODES + 255) / 256;
    int eb = (N_EDGES + 255) / 256;

    k_init<<<nb, 256, 0, stream>>>(deg, fill, N_NODES);
    k_count<<<eb, 256, 0, stream>>>(col, deg, N_EDGES);
    k_dis<<<nb, 256, 0, stream>>>(deg, dis, N_NODES);
    k_scan<<<1, 1024, 0, stream>>>(deg, offs, N_NODES);
    k_scatter<<<eb, 256, 0, stream>>>(row, col, offs, fill, srcl, N_EDGES);

    // conversions
    int xn4 = N_NODES * IN_C / 4;
    k_f2b4<<<(xn4 + 255) / 256, 256, 0, stream>>>(x, xb, xn4);
    k_wt<<<(IN_C * HID + 255) / 256, 256, 0, stream>>>(enc_w, enc_t, IN_C, HID);
    for (int l = 0; l < NLAYER; ++l)
        k_wt<<<(HID * HID + 255) / 256, 256, 0, stream>>>(
            conv_w + (size_t)l * HID * HID, conv_t + (size_t)l * HID * HID, HID, HID);
    k_wt<<<(HID * (HID / 2) + 255) / 256, 256, 0, stream>>>(w1, lin1_t, HID, HID / 2);

    // encoder: h = bf16(x @ enc_w + enc_b)
    {
        dim3 g((N_NODES + 127) / 128, HID / 128);
        k_mm<0><<<g, 256, 0, stream>>>(xb, enc_t, enc_b, nullptr, hb, N_NODES, IN_C, HID);
    }

    for (int l = 0; l < NLAYER; ++l) {
        dim3 g((N_NODES + 127) / 128, HID / 128);
        k_mm<1><<<g, 256, 0, stream>>>(hb, conv_t + (size_t)l * HID * HID, nullptr, dis,
                                       hw, N_NODES, HID, HID);
        k_agg<<<(N_NODES * 64 + 255) / 256, 256, 0, stream>>>(
            hw, srcl, offs, dis, conv_b + l * HID, ln_g + l * HID, ln_b + l * HID, hb, N_NODES);
    }

    // head
    {
        dim3 g((N_NODES + 127) / 128, 1);
        k_mm<2><<<g, 256, 0, stream>>>(hb, lin1_t, b1, nullptr, hid1, N_NODES, HID, HID / 2);
    }
    k_lin2<<<(N_NODES * 64 + 255) / 256, 256, 0, stream>>>(hid1, w2, b2, out, N_NODES);
}